// Round 1
// baseline (3708.406 us; speedup 1.0000x reference)
//
#include <hip/hip_runtime.h>

#define NP 60
#define PF 30
#define DE_ 20
#define DO_ 24
#define HID_ 60
#define NR_ 3540

// LDS layout (in floats)
#define X_OFF   0       // 1800   x[f*60+p]
#define A_OFF   1800    // 3600   A[p*60+h]  (includes fr_b1)
#define B_OFF   5400    // 3600   B[p*60+h]
#define W2_OFF  9000    // 3600   staged fr_w1, then fr_w2
#define W3_OFF  12600   // 1200   fr_w3
#define B2_OFF  13800   // 60
#define B3_OFF  13860   // 20
#define EB_OFF  13880   // 1200   Ebar[p*20+d]
#define O_OFF   15080   // 24
#define LDS_FLOATS 15104
// overlay (valid only after pair phase; reuses A/B/W2/W3 regions)
#define G1_OFF  1800    // 3600 scratch g1[p*60+h]
#define F1_OFF  5400    // 3000 fo_w1
#define F2_OFF  8400    // 3600 fo_w2
#define F3_OFF  12000   // 1440 fo_w3
#define FB1_OFF 13440   // 60
#define FB2_OFF 13500   // 60
#define FB3_OFF 13560   // 24

__global__ __launch_bounds__(256, 2)
void innet_kernel(const float* __restrict__ x,
                  const float* __restrict__ fr_w1, const float* __restrict__ fr_b1,
                  const float* __restrict__ fr_w2, const float* __restrict__ fr_b2,
                  const float* __restrict__ fr_w3, const float* __restrict__ fr_b3,
                  const float* __restrict__ fo_w1, const float* __restrict__ fo_b1,
                  const float* __restrict__ fo_w2, const float* __restrict__ fo_b2,
                  const float* __restrict__ fo_w3, const float* __restrict__ fo_b3,
                  float* __restrict__ out)
{
    __shared__ __align__(16) float s[LDS_FLOATS];
    const int b = blockIdx.x;
    const int tid = threadIdx.x;

    // ---- phase 0: load x slice, stage fr_w1 into W2 region, zero accumulators
    const float* xb = x + b * (PF * NP);
    for (int i = tid; i < PF * NP; i += 256) s[X_OFF + i] = xb[i];
    for (int i = tid; i < 3600; i += 256)    s[W2_OFF + i] = fr_w1[i];
    for (int i = tid; i < NP * DE_; i += 256) s[EB_OFF + i] = 0.0f;
    if (tid < DO_) s[O_OFF + tid] = 0.0f;
    __syncthreads();

    // ---- phase 1: A[p][h] = b1[h] + sum_f x[f][p]*W1[f][h]; B[p][h] = sum_f x[f][p]*W1[30+f][h]
    for (int idx = tid; idx < 7200; idx += 256) {
        const int which = (idx >= 3600) ? 1 : 0;
        const int rem = idx - which * 3600;
        const int p = rem / 60;
        const int h = rem - p * 60;
        float acc = which ? 0.0f : fr_b1[h];
        const float* w  = &s[W2_OFF + which * 1800 + h];
        const float* xs = &s[X_OFF + p];
        #pragma unroll
        for (int f = 0; f < PF; ++f) acc += xs[f * 60] * w[f * 60];
        s[(which ? B_OFF : A_OFF) + rem] = acc;
    }
    __syncthreads();

    // ---- phase 2: real fr weights into LDS
    for (int i = tid; i < 3600; i += 256) s[W2_OFF + i] = fr_w2[i];
    for (int i = tid; i < 1200; i += 256) s[W3_OFF + i] = fr_w3[i];
    if (tid < HID_) s[B2_OFF + tid] = fr_b2[tid];
    if (tid < DE_)  s[B3_OFF + tid] = fr_b3[tid];
    __syncthreads();

    // ---- phase 3: pair loop. thread t owns pairs [t*14, t*14+14)
    const int start = min(tid * 14, NR_);
    const int end   = min(start + 14, NR_);
    float eacc[DE_];
    #pragma unroll
    for (int d = 0; d < DE_; ++d) eacc[d] = 0.0f;
    int curr = -1;

    #pragma unroll 1
    for (int q = start; q < end; ++q) {
        const int r = q / 59;
        const int t = q - r * 59;
        const int sp = t + (t >= r ? 1 : 0);
        if (r != curr) {
            if (curr >= 0) {
                #pragma unroll
                for (int d = 0; d < DE_; ++d) {
                    atomicAdd(&s[EB_OFF + curr * DE_ + d], eacc[d]);
                    eacc[d] = 0.0f;
                }
            }
            curr = r;
        }
        // layer 2: h2 = b2 + relu(A_r + B_s) @ W2   (h1 recomputed on the fly)
        float h2[HID_];
        #pragma unroll
        for (int i = 0; i < HID_; ++i) h2[i] = s[B2_OFF + i];
        const float* Ar = &s[A_OFF + r * 60];
        const float* Bs = &s[B_OFF + sp * 60];
        #pragma unroll 1
        for (int jj = 0; jj < 15; ++jj) {
            const float4 a4 = *(const float4*)(Ar + jj * 4);
            const float4 b4 = *(const float4*)(Bs + jj * 4);
            float v[4];
            v[0] = fmaxf(a4.x + b4.x, 0.0f);
            v[1] = fmaxf(a4.y + b4.y, 0.0f);
            v[2] = fmaxf(a4.z + b4.z, 0.0f);
            v[3] = fmaxf(a4.w + b4.w, 0.0f);
            #pragma unroll
            for (int u = 0; u < 4; ++u) {
                const float4* w = (const float4*)&s[W2_OFF + (jj * 4 + u) * 60];
                #pragma unroll
                for (int i4 = 0; i4 < 15; ++i4) {
                    const float4 ww = w[i4];
                    h2[i4 * 4 + 0] += v[u] * ww.x;
                    h2[i4 * 4 + 1] += v[u] * ww.y;
                    h2[i4 * 4 + 2] += v[u] * ww.z;
                    h2[i4 * 4 + 3] += v[u] * ww.w;
                }
            }
        }
        // layer 3: e = relu(h2) @ W3 + b3 ; accumulate relu(e)
        float e[DE_];
        #pragma unroll
        for (int d = 0; d < DE_; ++d) e[d] = s[B3_OFF + d];
        #pragma unroll
        for (int i = 0; i < HID_; ++i) {
            const float v = fmaxf(h2[i], 0.0f);
            const float4* w = (const float4*)&s[W3_OFF + i * DE_];
            #pragma unroll
            for (int d4 = 0; d4 < 5; ++d4) {
                const float4 ww = w[d4];
                e[d4 * 4 + 0] += v * ww.x;
                e[d4 * 4 + 1] += v * ww.y;
                e[d4 * 4 + 2] += v * ww.z;
                e[d4 * 4 + 3] += v * ww.w;
            }
        }
        #pragma unroll
        for (int d = 0; d < DE_; ++d) eacc[d] += fmaxf(e[d], 0.0f);
    }
    if (curr >= 0) {
        #pragma unroll
        for (int d = 0; d < DE_; ++d) atomicAdd(&s[EB_OFF + curr * DE_ + d], eacc[d]);
    }
    __syncthreads();

    // ---- phase 4: stage fo weights into freed regions
    for (int i = tid; i < 3000; i += 256) s[F1_OFF + i] = fo_w1[i];
    for (int i = tid; i < 3600; i += 256) s[F2_OFF + i] = fo_w2[i];
    for (int i = tid; i < 1440; i += 256) s[F3_OFF + i] = fo_w3[i];
    if (tid < HID_) s[FB1_OFF + tid] = fo_b1[tid];
    if (tid < HID_) s[FB2_OFF + tid] = fo_b2[tid];
    if (tid < DO_)  s[FB3_OFF + tid] = fo_b3[tid];
    __syncthreads();

    // ---- phase 5: output MLP, one lane per particle
    if (tid < NP) {
        const int p = tid;
        // g1 = relu([x_p, Ebar_p] @ fo_w1 + b1)  -> LDS scratch
        #pragma unroll 1
        for (int h = 0; h < HID_; ++h) {
            float acc = s[FB1_OFF + h];
            #pragma unroll 1
            for (int k = 0; k < PF; ++k)
                acc += s[X_OFF + k * 60 + p] * s[F1_OFF + k * 60 + h];
            #pragma unroll
            for (int d = 0; d < DE_; ++d)
                acc += s[EB_OFF + p * DE_ + d] * s[F1_OFF + (PF + d) * 60 + h];
            s[G1_OFF + p * 60 + h] = fmaxf(acc, 0.0f);
        }
        // g2 = g1 @ fo_w2 + b2 (registers)
        float g2[HID_];
        #pragma unroll
        for (int i = 0; i < HID_; ++i) g2[i] = s[FB2_OFF + i];
        #pragma unroll 1
        for (int j = 0; j < HID_; ++j) {
            const float v = s[G1_OFF + p * 60 + j];
            const float4* w = (const float4*)&s[F2_OFF + j * 60];
            #pragma unroll
            for (int i4 = 0; i4 < 15; ++i4) {
                const float4 ww = w[i4];
                g2[i4 * 4 + 0] += v * ww.x;
                g2[i4 * 4 + 1] += v * ww.y;
                g2[i4 * 4 + 2] += v * ww.z;
                g2[i4 * 4 + 3] += v * ww.w;
            }
        }
        // o = relu(relu(g2) @ fo_w3 + b3); accumulate into block output
        float o[DO_];
        #pragma unroll
        for (int d = 0; d < DO_; ++d) o[d] = s[FB3_OFF + d];
        #pragma unroll
        for (int i = 0; i < HID_; ++i) {
            const float v = fmaxf(g2[i], 0.0f);
            const float4* w = (const float4*)&s[F3_OFF + i * DO_];
            #pragma unroll
            for (int d4 = 0; d4 < 6; ++d4) {
                const float4 ww = w[d4];
                o[d4 * 4 + 0] += v * ww.x;
                o[d4 * 4 + 1] += v * ww.y;
                o[d4 * 4 + 2] += v * ww.z;
                o[d4 * 4 + 3] += v * ww.w;
            }
        }
        #pragma unroll
        for (int d = 0; d < DO_; ++d) atomicAdd(&s[O_OFF + d], fmaxf(o[d], 0.0f));
    }
    __syncthreads();
    if (tid < DO_) out[b * DO_ + tid] = s[O_OFF + tid];
}

extern "C" void kernel_launch(void* const* d_in, const int* in_sizes, int n_in,
                              void* d_out, int out_size, void* d_ws, size_t ws_size,
                              hipStream_t stream) {
    const float* x      = (const float*)d_in[0];
    const float* fr_w1  = (const float*)d_in[1];
    const float* fr_b1  = (const float*)d_in[2];
    const float* fr_w2  = (const float*)d_in[3];
    const float* fr_b2  = (const float*)d_in[4];
    const float* fr_w3  = (const float*)d_in[5];
    const float* fr_b3  = (const float*)d_in[6];
    const float* fo_w1  = (const float*)d_in[7];
    const float* fo_b1  = (const float*)d_in[8];
    const float* fo_w2  = (const float*)d_in[9];
    const float* fo_b2  = (const float*)d_in[10];
    const float* fo_w3  = (const float*)d_in[11];
    const float* fo_b3  = (const float*)d_in[12];
    float* out = (float*)d_out;

    const int B = in_sizes[0] / (PF * NP);
    innet_kernel<<<dim3(B), dim3(256), 0, stream>>>(
        x, fr_w1, fr_b1, fr_w2, fr_b2, fr_w3, fr_b3,
        fo_w1, fo_b1, fo_w2, fo_b2, fo_w3, fo_b3, out);
}

// Round 2
// 1882.330 us; speedup vs baseline: 1.9701x; 1.9701x over previous
//
#include <hip/hip_runtime.h>

#define NP 60
#define PF 30
#define DE_ 20
#define DO_ 24
#define HID_ 60
#define NR_ 3540

// LDS layout (in floats)
#define X_OFF   0       // 1800   x[f*60+p]
#define A_OFF   1800    // 3600   A[p*60+h]  (includes fr_b1)
#define B_OFF   5400    // 3600   B[p*60+h]
#define W2_OFF  9000    // 3600   staged fr_w1, then fr_w2
#define W3_OFF  12600   // 1200   fr_w3
#define B2_OFF  13800   // 60
#define B3_OFF  13860   // 20
#define EB_OFF  13880   // 1200   Ebar[p*20+d]
#define O_OFF   15080   // 24
#define LDS_FLOATS 15104
// overlay (valid only after pair phase; reuses A/B/W2/W3 regions)
#define G1_OFF  1800    // 3600 scratch g1[p*60+h]
#define F1_OFF  5400    // 3000 fo_w1
#define F2_OFF  8400    // 3600 fo_w2
#define F3_OFF  12000   // 1440 fo_w3
#define FB1_OFF 13440   // 60
#define FB2_OFF 13500   // 60
#define FB3_OFF 13560   // 24

__global__ __launch_bounds__(256, 2)
void innet_kernel(const float* __restrict__ x,
                  const float* __restrict__ fr_w1, const float* __restrict__ fr_b1,
                  const float* __restrict__ fr_w2, const float* __restrict__ fr_b2,
                  const float* __restrict__ fr_w3, const float* __restrict__ fr_b3,
                  const float* __restrict__ fo_w1, const float* __restrict__ fo_b1,
                  const float* __restrict__ fo_w2, const float* __restrict__ fo_b2,
                  const float* __restrict__ fo_w3, const float* __restrict__ fo_b3,
                  float* __restrict__ out)
{
    __shared__ __align__(16) float s[LDS_FLOATS];
    const int b = blockIdx.x;
    const int tid = threadIdx.x;

    // ---- phase 0: load x slice, stage fr_w1 into W2 region, zero accumulators
    const float* xb = x + b * (PF * NP);
    for (int i = tid; i < PF * NP; i += 256) s[X_OFF + i] = xb[i];
    for (int i = tid; i < 3600; i += 256)    s[W2_OFF + i] = fr_w1[i];
    for (int i = tid; i < NP * DE_; i += 256) s[EB_OFF + i] = 0.0f;
    if (tid < DO_) s[O_OFF + tid] = 0.0f;
    __syncthreads();

    // ---- phase 1: A[p][h] = b1[h] + sum_f x[f][p]*W1[f][h]; B[p][h] = sum_f x[f][p]*W1[30+f][h]
    for (int idx = tid; idx < 7200; idx += 256) {
        const int which = (idx >= 3600) ? 1 : 0;
        const int rem = idx - which * 3600;
        const int p = rem / 60;
        const int h = rem - p * 60;
        float acc = which ? 0.0f : fr_b1[h];
        const float* w  = &s[W2_OFF + which * 1800 + h];
        const float* xs = &s[X_OFF + p];
        #pragma unroll
        for (int f = 0; f < PF; ++f) acc += xs[f * 60] * w[f * 60];
        s[(which ? B_OFF : A_OFF) + rem] = acc;
    }
    __syncthreads();

    // ---- phase 2: real fr weights into LDS
    for (int i = tid; i < 3600; i += 256) s[W2_OFF + i] = fr_w2[i];
    for (int i = tid; i < 1200; i += 256) s[W3_OFF + i] = fr_w3[i];
    if (tid < HID_) s[B2_OFF + tid] = fr_b2[tid];
    if (tid < DE_)  s[B3_OFF + tid] = fr_b3[tid];
    __syncthreads();

    // ---- phase 3: pair loop. thread t owns pairs [t*14, t*14+14).
    // Layer-2 output chunked by 20 so live regs = h[20]+e[20]+eacc[20] (no spill).
    const int start = min(tid * 14, NR_);
    const int end   = min(start + 14, NR_);
    float eacc[DE_];
    #pragma unroll
    for (int d = 0; d < DE_; ++d) eacc[d] = 0.0f;
    int curr = -1;

    #pragma unroll 1
    for (int q = start; q < end; ++q) {
        const int r = q / 59;
        const int t = q - r * 59;
        const int sp = t + (t >= r ? 1 : 0);
        if (r != curr) {
            if (curr >= 0) {
                #pragma unroll
                for (int d = 0; d < DE_; ++d) {
                    atomicAdd(&s[EB_OFF + curr * DE_ + d], eacc[d]);
                    eacc[d] = 0.0f;
                }
            }
            curr = r;
        }
        const float* Ar = &s[A_OFF + r * 60];
        const float* Bs = &s[B_OFF + sp * 60];
        float e[DE_];
        #pragma unroll
        for (int d = 0; d < DE_; ++d) e[d] = s[B3_OFF + d];

        #pragma unroll 1
        for (int c = 0; c < 3; ++c) {
            // h chunk = layer-2 outputs [c*20, c*20+20)
            float h[20];
            #pragma unroll
            for (int k = 0; k < 20; ++k) h[k] = s[B2_OFF + c * 20 + k];
            #pragma unroll 1
            for (int jj = 0; jj < 15; ++jj) {
                const float4 a4 = *(const float4*)(Ar + jj * 4);
                const float4 b4 = *(const float4*)(Bs + jj * 4);
                float v[4];
                v[0] = fmaxf(a4.x + b4.x, 0.0f);
                v[1] = fmaxf(a4.y + b4.y, 0.0f);
                v[2] = fmaxf(a4.z + b4.z, 0.0f);
                v[3] = fmaxf(a4.w + b4.w, 0.0f);
                #pragma unroll
                for (int u = 0; u < 4; ++u) {
                    const float4* w = (const float4*)&s[W2_OFF + (jj * 4 + u) * 60 + c * 20];
                    #pragma unroll
                    for (int k4 = 0; k4 < 5; ++k4) {
                        const float4 ww = w[k4];
                        h[k4 * 4 + 0] += v[u] * ww.x;
                        h[k4 * 4 + 1] += v[u] * ww.y;
                        h[k4 * 4 + 2] += v[u] * ww.z;
                        h[k4 * 4 + 3] += v[u] * ww.w;
                    }
                }
            }
            // layer 3 rows [c*20, c*20+20): e += relu(h_chunk) @ W3_chunk
            #pragma unroll 1
            for (int i = 0; i < 20; ++i) {
                const float v = fmaxf(h[i], 0.0f);
                const float4* w = (const float4*)&s[W3_OFF + (c * 20 + i) * DE_];
                #pragma unroll
                for (int d4 = 0; d4 < 5; ++d4) {
                    const float4 ww = w[d4];
                    e[d4 * 4 + 0] += v * ww.x;
                    e[d4 * 4 + 1] += v * ww.y;
                    e[d4 * 4 + 2] += v * ww.z;
                    e[d4 * 4 + 3] += v * ww.w;
                }
            }
        }
        #pragma unroll
        for (int d = 0; d < DE_; ++d) eacc[d] += fmaxf(e[d], 0.0f);
    }
    if (curr >= 0) {
        #pragma unroll
        for (int d = 0; d < DE_; ++d) atomicAdd(&s[EB_OFF + curr * DE_ + d], eacc[d]);
    }
    __syncthreads();

    // ---- phase 4: stage fo weights into freed regions
    for (int i = tid; i < 3000; i += 256) s[F1_OFF + i] = fo_w1[i];
    for (int i = tid; i < 3600; i += 256) s[F2_OFF + i] = fo_w2[i];
    for (int i = tid; i < 1440; i += 256) s[F3_OFF + i] = fo_w3[i];
    if (tid < HID_) s[FB1_OFF + tid] = fo_b1[tid];
    if (tid < HID_) s[FB2_OFF + tid] = fo_b2[tid];
    if (tid < DO_)  s[FB3_OFF + tid] = fo_b3[tid];
    __syncthreads();

    // ---- phase 5: output MLP, one lane per particle (chunked, no g2[60])
    if (tid < NP) {
        const int p = tid;
        // g1 = relu([x_p, Ebar_p] @ fo_w1 + b1)  -> LDS scratch
        #pragma unroll 1
        for (int h = 0; h < HID_; ++h) {
            float acc = s[FB1_OFF + h];
            #pragma unroll 1
            for (int k = 0; k < PF; ++k)
                acc += s[X_OFF + k * 60 + p] * s[F1_OFF + k * 60 + h];
            #pragma unroll
            for (int d = 0; d < DE_; ++d)
                acc += s[EB_OFF + p * DE_ + d] * s[F1_OFF + (PF + d) * 60 + h];
            s[G1_OFF + p * 60 + h] = fmaxf(acc, 0.0f);
        }
        float o[DO_];
        #pragma unroll
        for (int d = 0; d < DO_; ++d) o[d] = s[FB3_OFF + d];
        #pragma unroll 1
        for (int c = 0; c < 3; ++c) {
            float g2[20];
            #pragma unroll
            for (int k = 0; k < 20; ++k) g2[k] = s[FB2_OFF + c * 20 + k];
            #pragma unroll 1
            for (int j = 0; j < HID_; ++j) {
                const float v = s[G1_OFF + p * 60 + j];
                const float4* w = (const float4*)&s[F2_OFF + j * 60 + c * 20];
                #pragma unroll
                for (int k4 = 0; k4 < 5; ++k4) {
                    const float4 ww = w[k4];
                    g2[k4 * 4 + 0] += v * ww.x;
                    g2[k4 * 4 + 1] += v * ww.y;
                    g2[k4 * 4 + 2] += v * ww.z;
                    g2[k4 * 4 + 3] += v * ww.w;
                }
            }
            #pragma unroll 1
            for (int i = 0; i < 20; ++i) {
                const float v = fmaxf(g2[i], 0.0f);
                const float4* w = (const float4*)&s[F3_OFF + (c * 20 + i) * DO_];
                #pragma unroll
                for (int d4 = 0; d4 < 6; ++d4) {
                    const float4 ww = w[d4];
                    o[d4 * 4 + 0] += v * ww.x;
                    o[d4 * 4 + 1] += v * ww.y;
                    o[d4 * 4 + 2] += v * ww.z;
                    o[d4 * 4 + 3] += v * ww.w;
                }
            }
        }
        #pragma unroll
        for (int d = 0; d < DO_; ++d) atomicAdd(&s[O_OFF + d], fmaxf(o[d], 0.0f));
    }
    __syncthreads();
    if (tid < DO_) out[b * DO_ + tid] = s[O_OFF + tid];
}

extern "C" void kernel_launch(void* const* d_in, const int* in_sizes, int n_in,
                              void* d_out, int out_size, void* d_ws, size_t ws_size,
                              hipStream_t stream) {
    const float* x      = (const float*)d_in[0];
    const float* fr_w1  = (const float*)d_in[1];
    const float* fr_b1  = (const float*)d_in[2];
    const float* fr_w2  = (const float*)d_in[3];
    const float* fr_b2  = (const float*)d_in[4];
    const float* fr_w3  = (const float*)d_in[5];
    const float* fr_b3  = (const float*)d_in[6];
    const float* fo_w1  = (const float*)d_in[7];
    const float* fo_b1  = (const float*)d_in[8];
    const float* fo_w2  = (const float*)d_in[9];
    const float* fo_b2  = (const float*)d_in[10];
    const float* fo_w3  = (const float*)d_in[11];
    const float* fo_b3  = (const float*)d_in[12];
    float* out = (float*)d_out;

    const int B = in_sizes[0] / (PF * NP);
    innet_kernel<<<dim3(B), dim3(256), 0, stream>>>(
        x, fr_w1, fr_b1, fr_w2, fr_b2, fr_w3, fr_b3,
        fo_w1, fo_b1, fo_w2, fo_b2, fo_w3, fo_b3, out);
}

// Round 3
// 992.081 us; speedup vs baseline: 3.7380x; 1.8974x over previous
//
#include <hip/hip_runtime.h>

#define NP 60
#define PF 30
#define DE_ 20
#define DO_ 24
#define HID_ 60
#define STR 68        // f32 row stride for A/B panels
#define HTS 68        // bf16 row stride for per-wave Ht tile

typedef __bf16 bf16x8 __attribute__((ext_vector_type(8)));
typedef float  f32x4  __attribute__((ext_vector_type(4)));
typedef unsigned int u32x4 __attribute__((ext_vector_type(4)));

// ---- LDS layout (float indices) ----
#define X_OFF    0                   // 1800  x[f*60+p]
#define A_OFF    1800                // 4080  A[r][0..67] (cols 60..67 = 0)
#define B_OFF    5880                // 4080  B[s][0..67]
#define EB_OFF   9960                // 1200  Ebar[p*20+d]
#define HT_OFF   11160               // 2176  4 waves * 16*68 bf16
#define G1_OFF   13336               // 3600  W1 staging (ph1) / g1 scratch (ph5)
#define FB_OFF   16936               // 144   fo_b1(60) fo_b2(60) fo_b3(24)
#define O_OFF    17080               // 24
#define LDS_FLOATS 17104
// phase-5 weight overlay over A/B panels (contiguous 8160 floats)
#define F1O  A_OFF            // 3000
#define F2O  (A_OFF + 3000)   // 3600
#define F3O  (A_OFF + 6600)   // 1440
#define FB1O FB_OFF
#define FB2O (FB_OFF + 60)
#define FB3O (FB_OFF + 120)

__global__ __launch_bounds__(256, 2)
void innet_kernel(const float* __restrict__ x,
                  const float* __restrict__ fr_w1, const float* __restrict__ fr_b1,
                  const float* __restrict__ fr_w2, const float* __restrict__ fr_b2,
                  const float* __restrict__ fr_w3, const float* __restrict__ fr_b3,
                  const float* __restrict__ fo_w1, const float* __restrict__ fo_b1,
                  const float* __restrict__ fo_w2, const float* __restrict__ fo_b2,
                  const float* __restrict__ fo_w3, const float* __restrict__ fo_b3,
                  float* __restrict__ out)
{
    __shared__ __align__(16) float s[LDS_FLOATS];
    const int b   = blockIdx.x;
    const int tid = threadIdx.x;
    const int lane15 = tid & 15;
    const int g4     = (tid >> 4) & 3;
    const int w      = tid >> 6;

    // ---- preload fr MLP weight fragments (registers, global L2 reads) ----
    // B-frag layout: lane holds Bm[k = c*32 + g4*8 + j][col = n*16 + lane15]
    bf16x8 w2f[4][2];
    #pragma unroll
    for (int n = 0; n < 4; ++n) {
        const int col = n * 16 + lane15;
        #pragma unroll
        for (int c = 0; c < 2; ++c) {
            #pragma unroll
            for (int j = 0; j < 8; ++j) {
                const int k = c * 32 + g4 * 8 + j;
                float v = (k < HID_ && col < HID_) ? fr_w2[k * HID_ + col] : 0.0f;
                w2f[n][c][j] = (__bf16)v;
            }
        }
    }
    bf16x8 w3f[2][2];
    #pragma unroll
    for (int n = 0; n < 2; ++n) {
        const int col = n * 16 + lane15;
        #pragma unroll
        for (int c = 0; c < 2; ++c) {
            #pragma unroll
            for (int j = 0; j < 8; ++j) {
                const int k = c * 32 + g4 * 8 + j;
                float v = (k < HID_ && col < DE_) ? fr_w3[k * DE_ + col] : 0.0f;
                w3f[n][c][j] = (__bf16)v;
            }
        }
    }
    float b2v[4], b3v[2];
    #pragma unroll
    for (int n = 0; n < 4; ++n) {
        const int col = n * 16 + lane15;
        b2v[n] = (col < HID_) ? fr_b2[col] : 0.0f;
    }
    #pragma unroll
    for (int n = 0; n < 2; ++n) {
        const int col = n * 16 + lane15;
        b3v[n] = (col < DE_) ? fr_b3[col] : 0.0f;
    }

    // ---- phase 0: stage x, W1 (into G1 region), zero EB/O and A/B col-pads ----
    const float* xb = x + b * (PF * NP);
    for (int i = tid; i < PF * NP; i += 256) s[X_OFF + i] = xb[i];
    for (int i = tid; i < 3600; i += 256)    s[G1_OFF + i] = fr_w1[i];
    for (int i = tid; i < NP * DE_; i += 256) s[EB_OFF + i] = 0.0f;
    for (int i = tid; i < 960; i += 256) {     // zero cols 60..67 of A and B
        const int arr = i >> 9 >= 1 ? 1 : (i / 480);     // i/480: 0 or 1
        const int rem = i - arr * 480;
        const int p = rem >> 3;
        const int c = rem & 7;
        s[(arr ? B_OFF : A_OFF) + p * STR + 60 + c] = 0.0f;
    }
    if (tid < DO_) s[O_OFF + tid] = 0.0f;
    __syncthreads();

    // ---- phase 1: A[p][h] = b1[h] + x_p@W1[:30]; B[p][h] = x_p@W1[30:] ----
    for (int idx = tid; idx < 7200; idx += 256) {
        const int which = (idx >= 3600) ? 1 : 0;
        const int rem = idx - which * 3600;
        const int p = rem / 60;
        const int h = rem - p * 60;
        float acc = which ? 0.0f : fr_b1[h];
        const float* wp = &s[G1_OFF + which * 1800 + h];
        const float* xs = &s[X_OFF + p];
        #pragma unroll
        for (int f = 0; f < PF; ++f) acc += xs[f * 60] * wp[f * 60];
        s[(which ? B_OFF : A_OFF) + p * STR + h] = acc;
    }
    __syncthreads();

    // ---- phase 2: MFMA pair phase. Full 60x60 grid, diagonal masked at scatter.
    short* sHtS = (short*)&s[HT_OFF];
    unsigned int* sHtU = (unsigned int*)&s[HT_OFF];
    const int wbS = w * (16 * HTS);     // short-index base of this wave's Ht
    const int wbU = w * (16 * (HTS / 2));

    #pragma unroll 1
    for (int t = w; t < 225; t += 4) {
        const int q0 = t * 16;
        // A-operand row for this lane: pair q = q0 + lane15 -> (r, s)
        const int q  = q0 + lane15;
        const int r  = q / 60;
        const int si = q - r * 60;
        bf16x8 af0, af1;
        {
            const float2* pa0 = (const float2*)&s[A_OFF + r * STR + g4 * 8];
            const float2* pb0 = (const float2*)&s[B_OFF + si * STR + g4 * 8];
            const float2* pa1 = (const float2*)&s[A_OFF + r * STR + 32 + g4 * 8];
            const float2* pb1 = (const float2*)&s[B_OFF + si * STR + 32 + g4 * 8];
            #pragma unroll
            for (int jj = 0; jj < 4; ++jj) {
                const float2 a0 = pa0[jj], bb0 = pb0[jj];
                af0[jj * 2 + 0] = (__bf16)fmaxf(a0.x + bb0.x, 0.0f);
                af0[jj * 2 + 1] = (__bf16)fmaxf(a0.y + bb0.y, 0.0f);
                const float2 a1 = pa1[jj], bb1 = pb1[jj];
                af1[jj * 2 + 0] = (__bf16)fmaxf(a1.x + bb1.x, 0.0f);
                af1[jj * 2 + 1] = (__bf16)fmaxf(a1.y + bb1.y, 0.0f);
            }
        }
        // layer 2: 4 N-tiles x 2 K
        f32x4 acc0 = {0.f,0.f,0.f,0.f}, acc1 = {0.f,0.f,0.f,0.f};
        f32x4 acc2 = {0.f,0.f,0.f,0.f}, acc3 = {0.f,0.f,0.f,0.f};
        acc0 = __builtin_amdgcn_mfma_f32_16x16x32_bf16(af0, w2f[0][0], acc0, 0, 0, 0);
        acc1 = __builtin_amdgcn_mfma_f32_16x16x32_bf16(af0, w2f[1][0], acc1, 0, 0, 0);
        acc2 = __builtin_amdgcn_mfma_f32_16x16x32_bf16(af0, w2f[2][0], acc2, 0, 0, 0);
        acc3 = __builtin_amdgcn_mfma_f32_16x16x32_bf16(af0, w2f[3][0], acc3, 0, 0, 0);
        acc0 = __builtin_amdgcn_mfma_f32_16x16x32_bf16(af1, w2f[0][1], acc0, 0, 0, 0);
        acc1 = __builtin_amdgcn_mfma_f32_16x16x32_bf16(af1, w2f[1][1], acc1, 0, 0, 0);
        acc2 = __builtin_amdgcn_mfma_f32_16x16x32_bf16(af1, w2f[2][1], acc2, 0, 0, 0);
        acc3 = __builtin_amdgcn_mfma_f32_16x16x32_bf16(af1, w2f[3][1], acc3, 0, 0, 0);

        // h2 = relu(acc + b2) -> per-wave Ht tile (bf16), cols>=60 zeroed
        #pragma unroll
        for (int n = 0; n < 4; ++n) {
            const f32x4 an = (n == 0) ? acc0 : (n == 1) ? acc1 : (n == 2) ? acc2 : acc3;
            const int colD = n * 16 + lane15;
            #pragma unroll
            for (int reg = 0; reg < 4; ++reg) {
                const int rowD = g4 * 4 + reg;
                float h2 = (colD < HID_) ? fmaxf(an[reg] + b2v[n], 0.0f) : 0.0f;
                sHtS[wbS + rowD * HTS + colD] = __builtin_bit_cast(short, (__bf16)h2);
            }
        }
        // per-wave write->read ordering (rule 18)
        asm volatile("s_waitcnt lgkmcnt(0)" ::: "memory");
        __builtin_amdgcn_sched_barrier(0);

        // layer 3: read h2 back as A-frags, 2 N-tiles x 2 K
        f32x4 accE0 = {0.f,0.f,0.f,0.f}, accE1 = {0.f,0.f,0.f,0.f};
        #pragma unroll
        for (int c = 0; c < 2; ++c) {
            const int ub = wbU + lane15 * (HTS / 2) + c * 16 + g4 * 4;
            u32x4 u;
            u[0] = sHtU[ub + 0]; u[1] = sHtU[ub + 1];
            u[2] = sHtU[ub + 2]; u[3] = sHtU[ub + 3];
            const bf16x8 hf = __builtin_bit_cast(bf16x8, u);
            accE0 = __builtin_amdgcn_mfma_f32_16x16x32_bf16(hf, w3f[0][c], accE0, 0, 0, 0);
            accE1 = __builtin_amdgcn_mfma_f32_16x16x32_bf16(hf, w3f[1][c], accE1, 0, 0, 0);
        }
        // scatter: E = relu(accE + b3), skip diagonal, run-sum over consecutive r
        #pragma unroll
        for (int n = 0; n < 2; ++n) {
            const f32x4 ae = (n == 0) ? accE0 : accE1;
            const int col = n * 16 + lane15;
            const bool cv = (col < DE_);
            float run = 0.0f;
            int pr = (q0 + g4 * 4) / 60;
            #pragma unroll
            for (int reg = 0; reg < 4; ++reg) {
                const int qq = q0 + g4 * 4 + reg;
                const int rr = qq / 60;
                const int ss = qq - rr * 60;
                float e = 0.0f;
                if (cv && ss != rr) e = fmaxf(ae[reg] + b3v[n], 0.0f);
                if (rr != pr) {
                    if (cv && run != 0.0f) atomicAdd(&s[EB_OFF + pr * DE_ + col], run);
                    run = 0.0f; pr = rr;
                }
                run += e;
            }
            if (cv && run != 0.0f) atomicAdd(&s[EB_OFF + pr * DE_ + col], run);
        }
    }
    __syncthreads();

    // ---- phase 4: stage fo weights over freed A/B panels ----
    for (int i = tid; i < 3000; i += 256) s[F1O + i] = fo_w1[i];
    for (int i = tid; i < 3600; i += 256) s[F2O + i] = fo_w2[i];
    for (int i = tid; i < 1440; i += 256) s[F3O + i] = fo_w3[i];
    if (tid < HID_) s[FB1O + tid] = fo_b1[tid];
    if (tid < HID_) s[FB2O + tid] = fo_b2[tid];
    if (tid < DO_)  s[FB3O + tid] = fo_b3[tid];
    __syncthreads();

    // ---- phase 5: output MLP, one lane per particle (round-2 form) ----
    if (tid < NP) {
        const int p = tid;
        #pragma unroll 1
        for (int h = 0; h < HID_; ++h) {
            float acc = s[FB1O + h];
            #pragma unroll 1
            for (int k = 0; k < PF; ++k)
                acc += s[X_OFF + k * 60 + p] * s[F1O + k * 60 + h];
            #pragma unroll
            for (int d = 0; d < DE_; ++d)
                acc += s[EB_OFF + p * DE_ + d] * s[F1O + (PF + d) * 60 + h];
            s[G1_OFF + p * 60 + h] = fmaxf(acc, 0.0f);
        }
        float o[DO_];
        #pragma unroll
        for (int d = 0; d < DO_; ++d) o[d] = s[FB3O + d];
        #pragma unroll 1
        for (int c = 0; c < 3; ++c) {
            float g2[20];
            #pragma unroll
            for (int k = 0; k < 20; ++k) g2[k] = s[FB2O + c * 20 + k];
            #pragma unroll 1
            for (int j = 0; j < HID_; ++j) {
                const float v = s[G1_OFF + p * 60 + j];
                const float4* wp = (const float4*)&s[F2O + j * 60 + c * 20];
                #pragma unroll
                for (int k4 = 0; k4 < 5; ++k4) {
                    const float4 ww = wp[k4];
                    g2[k4 * 4 + 0] += v * ww.x;
                    g2[k4 * 4 + 1] += v * ww.y;
                    g2[k4 * 4 + 2] += v * ww.z;
                    g2[k4 * 4 + 3] += v * ww.w;
                }
            }
            #pragma unroll 1
            for (int i = 0; i < 20; ++i) {
                const float v = fmaxf(g2[i], 0.0f);
                const float4* wp = (const float4*)&s[F3O + (c * 20 + i) * DO_];
                #pragma unroll
                for (int d4 = 0; d4 < 6; ++d4) {
                    const float4 ww = wp[d4];
                    o[d4 * 4 + 0] += v * ww.x;
                    o[d4 * 4 + 1] += v * ww.y;
                    o[d4 * 4 + 2] += v * ww.z;
                    o[d4 * 4 + 3] += v * ww.w;
                }
            }
        }
        #pragma unroll
        for (int d = 0; d < DO_; ++d) atomicAdd(&s[O_OFF + d], fmaxf(o[d], 0.0f));
    }
    __syncthreads();
    if (tid < DO_) out[b * DO_ + tid] = s[O_OFF + tid];
}

extern "C" void kernel_launch(void* const* d_in, const int* in_sizes, int n_in,
                              void* d_out, int out_size, void* d_ws, size_t ws_size,
                              hipStream_t stream) {
    const float* x      = (const float*)d_in[0];
    const float* fr_w1  = (const float*)d_in[1];
    const float* fr_b1  = (const float*)d_in[2];
    const float* fr_w2  = (const float*)d_in[3];
    const float* fr_b2  = (const float*)d_in[4];
    const float* fr_w3  = (const float*)d_in[5];
    const float* fr_b3  = (const float*)d_in[6];
    const float* fo_w1  = (const float*)d_in[7];
    const float* fo_b1  = (const float*)d_in[8];
    const float* fo_w2  = (const float*)d_in[9];
    const float* fo_b2  = (const float*)d_in[10];
    const float* fo_w3  = (const float*)d_in[11];
    const float* fo_b3  = (const float*)d_in[12];
    float* out = (float*)d_out;

    const int B = in_sizes[0] / (PF * NP);
    innet_kernel<<<dim3(B), dim3(256), 0, stream>>>(
        x, fr_w1, fr_b1, fr_w2, fr_b2, fr_w3, fr_b3,
        fo_w1, fo_b1, fo_w2, fo_b2, fo_w3, fo_b3, out);
}

// Round 5
// 316.820 us; speedup vs baseline: 11.7051x; 3.1314x over previous
//
#include <hip/hip_runtime.h>

typedef __bf16 bf16x8 __attribute__((ext_vector_type(8)));
typedef float  f32x4  __attribute__((ext_vector_type(4)));
typedef unsigned int u32x4 __attribute__((ext_vector_type(4)));

#define MFMA16 __builtin_amdgcn_mfma_f32_16x16x32_bf16

// ---- LDS layout ----
// unsigned short indices:
#define XT_S 0        // Xt[60][40] bf16 (cols 30..39 zero)
#define A_S  2400     // A[60][72] bf16 (cols 60..63 zero, 64..71 unused)
#define B_S  6720     // B[60][72] bf16
#define HT_S 11040    // 4 waves * [16][72] bf16
// float indices (short idx / 2):
#define EB_F 7824     // Ebar[60][20] f32
#define O_F  9024     // O[24] f32
#define NSH  18096    // total shorts = 36192 B (35.3 KB -> 4 blocks/CU)

__device__ __forceinline__ float bl(unsigned u){ return __builtin_bit_cast(float, u << 16); }
__device__ __forceinline__ float bh(unsigned u){ return __builtin_bit_cast(float, u & 0xffff0000u); }
__device__ __forceinline__ unsigned short bits16(float x){ return __builtin_bit_cast(unsigned short, (__bf16)x); }

__device__ __forceinline__ bf16x8 addrelu(u32x4 a, u32x4 b){
    bf16x8 o;
    #pragma unroll
    for (int k = 0; k < 4; ++k){
        const float lo = bl(a[k]) + bl(b[k]);
        const float hi = bh(a[k]) + bh(b[k]);
        o[2*k]   = (__bf16)fmaxf(lo, 0.f);
        o[2*k+1] = (__bf16)fmaxf(hi, 0.f);
    }
    return o;
}

__global__ __launch_bounds__(256, 4)
void innet_kernel(const float* __restrict__ x,
                  const float* __restrict__ fr_w1, const float* __restrict__ fr_b1,
                  const float* __restrict__ fr_w2, const float* __restrict__ fr_b2,
                  const float* __restrict__ fr_w3, const float* __restrict__ fr_b3,
                  const float* __restrict__ fo_w1, const float* __restrict__ fo_b1,
                  const float* __restrict__ fo_w2, const float* __restrict__ fo_b2,
                  const float* __restrict__ fo_w3, const float* __restrict__ fo_b3,
                  float* __restrict__ out)
{
    __shared__ __align__(16) unsigned short ss[NSH];
    float* sf = (float*)ss;

    const int b      = blockIdx.x;
    const int tid    = threadIdx.x;
    const int lane15 = tid & 15;
    const int g4     = (tid >> 4) & 3;
    const int w      = tid >> 6;
    const int wbS    = HT_S + w * 1152;      // per-wave Ht base (short idx)

    // ---- phase 0: stage x -> Xt bf16 [p][f], zero pads/EB/O ----
    const float* xb = x + b * 1800;
    for (int i = tid; i < 1800; i += 256){
        const int f = i / 60, p = i - f * 60;
        ss[XT_S + p * 40 + f] = bits16(xb[i]);
    }
    for (int i = tid; i < 600; i += 256){
        const int p = i / 10;
        ss[XT_S + p * 40 + 30 + (i - p * 10)] = 0;
    }
    for (int i = tid; i < 1200; i += 256) sf[EB_F + i] = 0.f;
    if (tid < 24) sf[O_F + tid] = 0.f;
    __syncthreads();

    // ---- phase 1: A/B panels via MFMA. wave w = M-tile rows [16w,16w+16) ----
    {
        bf16x8 w1af[4], w1bf[4];
        float b1v[4];
        #pragma unroll
        for (int n = 0; n < 4; ++n){
            const int col = n * 16 + lane15;
            const bool cvv = col < 60;
            b1v[n] = cvv ? fr_b1[col] : 0.f;
            #pragma unroll
            for (int j = 0; j < 8; ++j){
                const int f = g4 * 8 + j;
                w1af[n][j] = (__bf16)((f < 30 && cvv) ? fr_w1[f * 60 + col] : 0.f);
                w1bf[n][j] = (__bf16)((f < 30 && cvv) ? fr_w1[(30 + f) * 60 + col] : 0.f);
            }
        }
        const int pr_ = w * 16 + lane15;
        const u32x4 ux = *(const u32x4*)&ss[XT_S + pr_ * 40 + g4 * 8];
        const bf16x8 xa = __builtin_bit_cast(bf16x8, ux);
        const f32x4 z = {0.f, 0.f, 0.f, 0.f};
        f32x4 aA0 = MFMA16(xa, w1af[0], z, 0, 0, 0);
        f32x4 aA1 = MFMA16(xa, w1af[1], z, 0, 0, 0);
        f32x4 aA2 = MFMA16(xa, w1af[2], z, 0, 0, 0);
        f32x4 aA3 = MFMA16(xa, w1af[3], z, 0, 0, 0);
        f32x4 aB0 = MFMA16(xa, w1bf[0], z, 0, 0, 0);
        f32x4 aB1 = MFMA16(xa, w1bf[1], z, 0, 0, 0);
        f32x4 aB2 = MFMA16(xa, w1bf[2], z, 0, 0, 0);
        f32x4 aB3 = MFMA16(xa, w1bf[3], z, 0, 0, 0);
        #pragma unroll
        for (int reg = 0; reg < 4; ++reg){
            const int p = w * 16 + g4 * 4 + reg;
            if (p < 60){
                ss[A_S + p * 72 +      lane15] = bits16(aA0[reg] + b1v[0]);
                ss[A_S + p * 72 + 16 + lane15] = bits16(aA1[reg] + b1v[1]);
                ss[A_S + p * 72 + 32 + lane15] = bits16(aA2[reg] + b1v[2]);
                ss[A_S + p * 72 + 48 + lane15] = bits16(aA3[reg] + b1v[3]);
                ss[B_S + p * 72 +      lane15] = bits16(aB0[reg]);
                ss[B_S + p * 72 + 16 + lane15] = bits16(aB1[reg]);
                ss[B_S + p * 72 + 32 + lane15] = bits16(aB2[reg]);
                ss[B_S + p * 72 + 48 + lane15] = bits16(aB3[reg]);
            }
        }
    }
    __syncthreads();

    // ---- fr layer-2/3 weight fragments (registers) ----
    bf16x8 w2f[4][2], w3f[2][2];
    float b2v[4], b3v[2];
    #pragma unroll
    for (int n = 0; n < 4; ++n){
        const int col = n * 16 + lane15;
        b2v[n] = (col < 60) ? fr_b2[col] : 0.f;
        #pragma unroll
        for (int c = 0; c < 2; ++c){
            #pragma unroll
            for (int j = 0; j < 8; ++j){
                const int k = c * 32 + g4 * 8 + j;
                w2f[n][c][j] = (__bf16)((k < 60 && col < 60) ? fr_w2[k * 60 + col] : 0.f);
            }
        }
    }
    #pragma unroll
    for (int n = 0; n < 2; ++n){
        const int col = n * 16 + lane15;
        b3v[n] = (col < 20) ? fr_b3[col] : 0.f;
        #pragma unroll
        for (int c = 0; c < 2; ++c){
            #pragma unroll
            for (int j = 0; j < 8; ++j){
                const int k = c * 32 + g4 * 8 + j;
                w3f[n][c][j] = (__bf16)((k < 60 && col < 20) ? fr_w3[k * 20 + col] : 0.f);
            }
        }
    }

    auto writeHt = [&](const f32x4& a, float bias, int n){
        #pragma unroll
        for (int reg = 0; reg < 4; ++reg)
            ss[wbS + (g4 * 4 + reg) * 72 + n * 16 + lane15] = bits16(fmaxf(a[reg] + bias, 0.f));
    };
    auto scat = [&](const f32x4& ae, int n, int q0){
        const int col = n * 16 + lane15;
        const bool cv = (col < 20);
        float run = 0.f;
        int pr = (q0 + g4 * 4) / 60;
        #pragma unroll
        for (int reg = 0; reg < 4; ++reg){
            const int qq = q0 + g4 * 4 + reg;
            const int rr = qq / 60;
            const int si = qq - rr * 60;
            float e = 0.f;
            if (cv && si != rr) e = fmaxf(ae[reg] + b3v[n], 0.f);
            if (rr != pr){
                if (cv && run != 0.f) atomicAdd(&sf[EB_F + pr * 20 + col], run);
                run = 0.f; pr = rr;
            }
            run += e;
        }
        if (cv && run != 0.f) atomicAdd(&sf[EB_F + pr * 20 + col], run);
    };

    // ---- phase 2: pair loop over 225 16-row tiles of the 60x60 grid ----
    #pragma unroll 1
    for (int t = w; t < 225; t += 4){
        const int q0 = t * 16;
        const int q  = q0 + lane15;
        const int r  = q / 60;
        const int si = q - r * 60;
        const int ba = A_S + r  * 72 + g4 * 8;
        const int bb = B_S + si * 72 + g4 * 8;
        const u32x4 ra0 = *(const u32x4*)&ss[ba];
        const u32x4 rb0 = *(const u32x4*)&ss[bb];
        const u32x4 ra1 = *(const u32x4*)&ss[ba + 32];
        const u32x4 rb1 = *(const u32x4*)&ss[bb + 32];
        const bf16x8 af0 = addrelu(ra0, rb0);
        const bf16x8 af1 = addrelu(ra1, rb1);

        f32x4 acc0 = {0.f,0.f,0.f,0.f}, acc1 = {0.f,0.f,0.f,0.f};
        f32x4 acc2 = {0.f,0.f,0.f,0.f}, acc3 = {0.f,0.f,0.f,0.f};
        acc0 = MFMA16(af0, w2f[0][0], acc0, 0, 0, 0);
        acc1 = MFMA16(af0, w2f[1][0], acc1, 0, 0, 0);
        acc2 = MFMA16(af0, w2f[2][0], acc2, 0, 0, 0);
        acc3 = MFMA16(af0, w2f[3][0], acc3, 0, 0, 0);
        acc0 = MFMA16(af1, w2f[0][1], acc0, 0, 0, 0);
        acc1 = MFMA16(af1, w2f[1][1], acc1, 0, 0, 0);
        acc2 = MFMA16(af1, w2f[2][1], acc2, 0, 0, 0);
        acc3 = MFMA16(af1, w2f[3][1], acc3, 0, 0, 0);

        writeHt(acc0, b2v[0], 0);
        writeHt(acc1, b2v[1], 1);
        writeHt(acc2, b2v[2], 2);
        writeHt(acc3, b2v[3], 3);
        asm volatile("s_waitcnt lgkmcnt(0)" ::: "memory");
        __builtin_amdgcn_sched_barrier(0);

        const u32x4 h0 = *(const u32x4*)&ss[wbS + lane15 * 72 + g4 * 8];
        const u32x4 h1 = *(const u32x4*)&ss[wbS + lane15 * 72 + 32 + g4 * 8];
        const bf16x8 hf0 = __builtin_bit_cast(bf16x8, h0);
        const bf16x8 hf1 = __builtin_bit_cast(bf16x8, h1);
        f32x4 ae0 = {0.f,0.f,0.f,0.f}, ae1 = {0.f,0.f,0.f,0.f};
        ae0 = MFMA16(hf0, w3f[0][0], ae0, 0, 0, 0);
        ae1 = MFMA16(hf0, w3f[1][0], ae1, 0, 0, 0);
        ae0 = MFMA16(hf1, w3f[0][1], ae0, 0, 0, 0);
        ae1 = MFMA16(hf1, w3f[1][1], ae1, 0, 0, 0);

        scat(ae0, 0, q0);
        scat(ae1, 1, q0);
    }
    __syncthreads();

    // ---- phase 5: output MLP via MFMA. wave w = particle rows [16w,16w+16) ----
    {
        const int p5 = w * 16 + lane15;
        const int pe = (p5 < 60) ? p5 : 0;
        // A-frag for C = [x_p(30), Ebar_p(20)] padded to 64
        const u32x4 uc0 = *(const u32x4*)&ss[XT_S + pe * 40 + g4 * 8];
        bf16x8 ca0 = __builtin_bit_cast(bf16x8, uc0);
        if (g4 == 3){
            ca0[6] = (__bf16)sf[EB_F + pe * 20 + 0];
            ca0[7] = (__bf16)sf[EB_F + pe * 20 + 1];
        }
        bf16x8 ca1;
        #pragma unroll
        for (int j = 0; j < 8; ++j){
            const int d = 2 + g4 * 8 + j;
            ca1[j] = (d < 20) ? (__bf16)sf[EB_F + pe * 20 + d] : (__bf16)0.f;
        }
        // fo_w1 frags
        bf16x8 wf[4][2]; float bv[4];
        #pragma unroll
        for (int n = 0; n < 4; ++n){
            const int col = n * 16 + lane15;
            bv[n] = (col < 60) ? fo_b1[col] : 0.f;
            #pragma unroll
            for (int c = 0; c < 2; ++c){
                #pragma unroll
                for (int j = 0; j < 8; ++j){
                    const int k = c * 32 + g4 * 8 + j;
                    wf[n][c][j] = (__bf16)((k < 50 && col < 60) ? fo_w1[k * 60 + col] : 0.f);
                }
            }
        }
        f32x4 g0 = {0.f,0.f,0.f,0.f}, g1 = {0.f,0.f,0.f,0.f};
        f32x4 g2 = {0.f,0.f,0.f,0.f}, g3 = {0.f,0.f,0.f,0.f};
        g0 = MFMA16(ca0, wf[0][0], g0, 0, 0, 0);
        g1 = MFMA16(ca0, wf[1][0], g1, 0, 0, 0);
        g2 = MFMA16(ca0, wf[2][0], g2, 0, 0, 0);
        g3 = MFMA16(ca0, wf[3][0], g3, 0, 0, 0);
        g0 = MFMA16(ca1, wf[0][1], g0, 0, 0, 0);
        g1 = MFMA16(ca1, wf[1][1], g1, 0, 0, 0);
        g2 = MFMA16(ca1, wf[2][1], g2, 0, 0, 0);
        g3 = MFMA16(ca1, wf[3][1], g3, 0, 0, 0);
        writeHt(g0, bv[0], 0); writeHt(g1, bv[1], 1);
        writeHt(g2, bv[2], 2); writeHt(g3, bv[3], 3);
        asm volatile("s_waitcnt lgkmcnt(0)" ::: "memory");
        __builtin_amdgcn_sched_barrier(0);
        {
            const u32x4 h0 = *(const u32x4*)&ss[wbS + lane15 * 72 + g4 * 8];
            const u32x4 h1 = *(const u32x4*)&ss[wbS + lane15 * 72 + 32 + g4 * 8];
            const bf16x8 hf0 = __builtin_bit_cast(bf16x8, h0);
            const bf16x8 hf1 = __builtin_bit_cast(bf16x8, h1);
            // fo_w2 frags (reuse wf)
            #pragma unroll
            for (int n = 0; n < 4; ++n){
                const int col = n * 16 + lane15;
                bv[n] = (col < 60) ? fo_b2[col] : 0.f;
                #pragma unroll
                for (int c = 0; c < 2; ++c){
                    #pragma unroll
                    for (int j = 0; j < 8; ++j){
                        const int k = c * 32 + g4 * 8 + j;
                        wf[n][c][j] = (__bf16)((k < 60 && col < 60) ? fo_w2[k * 60 + col] : 0.f);
                    }
                }
            }
            g0 = (f32x4){0.f,0.f,0.f,0.f}; g1 = (f32x4){0.f,0.f,0.f,0.f};
            g2 = (f32x4){0.f,0.f,0.f,0.f}; g3 = (f32x4){0.f,0.f,0.f,0.f};
            g0 = MFMA16(hf0, wf[0][0], g0, 0, 0, 0);
            g1 = MFMA16(hf0, wf[1][0], g1, 0, 0, 0);
            g2 = MFMA16(hf0, wf[2][0], g2, 0, 0, 0);
            g3 = MFMA16(hf0, wf[3][0], g3, 0, 0, 0);
            g0 = MFMA16(hf1, wf[0][1], g0, 0, 0, 0);
            g1 = MFMA16(hf1, wf[1][1], g1, 0, 0, 0);
            g2 = MFMA16(hf1, wf[2][1], g2, 0, 0, 0);
            g3 = MFMA16(hf1, wf[3][1], g3, 0, 0, 0);
            writeHt(g0, bv[0], 0); writeHt(g1, bv[1], 1);
            writeHt(g2, bv[2], 2); writeHt(g3, bv[3], 3);
        }
        asm volatile("s_waitcnt lgkmcnt(0)" ::: "memory");
        __builtin_amdgcn_sched_barrier(0);
        {
            const u32x4 h0 = *(const u32x4*)&ss[wbS + lane15 * 72 + g4 * 8];
            const u32x4 h1 = *(const u32x4*)&ss[wbS + lane15 * 72 + 32 + g4 * 8];
            const bf16x8 hf0 = __builtin_bit_cast(bf16x8, h0);
            const bf16x8 hf1 = __builtin_bit_cast(bf16x8, h1);
            // fo_w3 frags (24 cols -> 2 N-tiles)
            bf16x8 w3o[2][2]; float bv3[2];
            #pragma unroll
            for (int n = 0; n < 2; ++n){
                const int col = n * 16 + lane15;
                bv3[n] = (col < 24) ? fo_b3[col] : 0.f;
                #pragma unroll
                for (int c = 0; c < 2; ++c){
                    #pragma unroll
                    for (int j = 0; j < 8; ++j){
                        const int k = c * 32 + g4 * 8 + j;
                        w3o[n][c][j] = (__bf16)((k < 60 && col < 24) ? fo_w3[k * 24 + col] : 0.f);
                    }
                }
            }
            f32x4 o0 = {0.f,0.f,0.f,0.f}, o1 = {0.f,0.f,0.f,0.f};
            o0 = MFMA16(hf0, w3o[0][0], o0, 0, 0, 0);
            o1 = MFMA16(hf0, w3o[1][0], o1, 0, 0, 0);
            o0 = MFMA16(hf1, w3o[0][1], o0, 0, 0, 0);
            o1 = MFMA16(hf1, w3o[1][1], o1, 0, 0, 0);
            #pragma unroll
            for (int n = 0; n < 2; ++n){
                const f32x4 on = (n == 0) ? o0 : o1;
                float ssum = 0.f;
                #pragma unroll
                for (int reg = 0; reg < 4; ++reg){
                    const int p = w * 16 + g4 * 4 + reg;
                    if (p < 60) ssum += fmaxf(on[reg] + bv3[n], 0.f);
                }
                ssum += __shfl_xor(ssum, 16);
                ssum += __shfl_xor(ssum, 32);
                if (g4 == 0){
                    const int col = n * 16 + lane15;
                    if (col < 24) atomicAdd(&sf[O_F + col], ssum);
                }
            }
        }
    }
    __syncthreads();
    if (tid < 24) out[(size_t)b * 24 + tid] = sf[O_F + tid];
}

extern "C" void kernel_launch(void* const* d_in, const int* in_sizes, int n_in,
                              void* d_out, int out_size, void* d_ws, size_t ws_size,
                              hipStream_t stream) {
    const float* x      = (const float*)d_in[0];
    const float* fr_w1  = (const float*)d_in[1];
    const float* fr_b1  = (const float*)d_in[2];
    const float* fr_w2  = (const float*)d_in[3];
    const float* fr_b2  = (const float*)d_in[4];
    const float* fr_w3  = (const float*)d_in[5];
    const float* fr_b3  = (const float*)d_in[6];
    const float* fo_w1  = (const float*)d_in[7];
    const float* fo_b1  = (const float*)d_in[8];
    const float* fo_w2  = (const float*)d_in[9];
    const float* fo_b2  = (const float*)d_in[10];
    const float* fo_w3  = (const float*)d_in[11];
    const float* fo_b3  = (const float*)d_in[12];
    float* out = (float*)d_out;

    const int B = in_sizes[0] / 1800;
    innet_kernel<<<dim3(B), dim3(256), 0, stream>>>(
        x, fr_w1, fr_b1, fr_w2, fr_b2, fr_w3, fr_b3,
        fo_w1, fo_b1, fo_w2, fo_b2, fo_w3, fo_b3, out);
}